// Round 4
// baseline (119.058 us; speedup 1.0000x reference)
//
#include <hip/hip_runtime.h>
#include <hip/hip_bf16.h>
#include <math.h>

// MMD (InfoVAE RBF kernel), N=8192, D=128, fp32 in, scalar fp32 out.
//
// Round 14: 256x256 tile with SIXTEEN r10-shaped waves (1024 thr) +
// K-sliced pre-swizzled Zs layout for contiguous 1-KB DMA issues.
//   r13 post-mortem: 256x256 with 8 fat waves (acc 8x4 = 128 AGPR + 124
//   VGPR = 252 regs) collapsed occupancy to 8 waves/CU -> reuse gain
//   cancelled. r10/r12 ran 16 waves/CU and were DMA-rate-bound (~2 MB/CU
//   staged at 12-16 B/cy on a stride-256 segment pattern ~= the whole
//   54-60 us).
//   Fix 1 (geometry): keep r10's per-wave shape (64x64 out, acc[4][4]
//   = 64 AGPR, a[4]+b[4] = 32 VGPR, ~120 regs measured in r10) x 16
//   waves in ONE block over a 256x256 tile: regs <=128 -> 4 waves/SIMD
//   -> 16 waves/CU AND 1.04 MB/CU DMA (halved).
//   Fix 2 (DMA rate): store Z as 4 K-slice planes Zs[s][row][64B] with
//   the chunk swizzle PRE-APPLIED at prep store (m173: pre-swizzled
//   global + linear DMA + XOR read). Each DMA issue = contiguous 1 KB
//   (m97-class, ~21 B/cy) instead of 16 x 64-B stride-256 segments.
//   Read-side swizzle byte-identical to r13's measured-0-conflict
//   csw = (quad^((lr>>1)&3))<<4; store chunk c' = quad^((row>>1)&3)
//   (panels start at row%8==0 so (p>>1)&3 == (row>>1)&3).
//   Sync: r12/r13 counted-vmcnt template, counts halved (STAGE = 2
//   issues/wave: A 1 KB + B 1 KB). 8 barriers/block over 16 waves.
//   Numerics: per-element MFMA K-chain (4x 16x16x32, ascending K) and
//   epilogue math identical to r10-r13; fp32 partials 32 terms; fp64
//   wave reduce + atomic into 256 spread slots. absmax expected
//   5.96e-8 (threshold 7.15e-8).

#define NN 8192
#define DD 128
#define TZ 16384
#define TILES 64                            // 256-row tiles
#define NBLOCKS (TILES * (TILES + 1) / 2)   // 2080

typedef __attribute__((ext_vector_type(8))) short bf16x8;
typedef __attribute__((ext_vector_type(4))) float f32x4;
typedef __attribute__((ext_vector_type(2))) float f32x2;

#if __has_builtin(__builtin_amdgcn_exp2f)
#define EXP2F __builtin_amdgcn_exp2f
#else
#define EXP2F exp2f
#endif

constexpr float LOG2E = 0x1.715476p+0f;
constexpr float S2 = LOG2E / 8192.0f;              // 2*log2e/16384

constexpr size_t PLANE = 1048576;                  // 16384 rows x 64 B

// ---- ws layout ----
constexpr size_t WS_NORM = 2048;                   // sums: 256 fp64 slots
constexpr size_t WS_Z    = WS_NORM + (size_t)TZ * sizeof(float);

__device__ __forceinline__ void gload_lds16(const void* g, void* l) {
  __builtin_amdgcn_global_load_lds(
      (const __attribute__((address_space(1))) void*)g,
      (__attribute__((address_space(3))) void*)l, 16, 0, 0);
}

__global__ __launch_bounds__(256) void prep(
    const float* __restrict__ X, const float* __restrict__ Y,
    char* __restrict__ Zs, float* __restrict__ normZ,
    double* __restrict__ sums) {
  if (blockIdx.x == 0) sums[threadIdx.x] = 0.0;    // 256 slots

  const int row = blockIdx.x * 4 + (threadIdx.x >> 6);
  const int lane = threadIdx.x & 63;
  const float* __restrict__ src =
      (row < NN) ? (X + (size_t)row * DD) : (Y + (size_t)(row - NN) * DD);
  const float2 v = *reinterpret_cast<const float2*>(src + 2 * lane);

  float n = v.x * v.x + v.y * v.y;

  // K-slice plane store, chunk pre-swizzled: col byte = lane*4 ->
  // plane ks = lane>>4, chunk quad = (lane>>2)&3, inner = (lane&3)*4.
  // Physical chunk = quad ^ ((row>>1)&3).
  const int ks = lane >> 4;
  const int quadc = (lane >> 2) & 3;
  const int inner = (lane & 3) * 4;
  char* dst = Zs + (size_t)ks * PLANE + (size_t)row * 64 +
              ((quadc ^ ((row >> 1) & 3)) << 4) + inner;
  *reinterpret_cast<__hip_bfloat162*>(dst) =
      __hip_bfloat162{__float2bfloat16(v.x), __float2bfloat16(v.y)};

#pragma unroll
  for (int o = 32; o > 0; o >>= 1) n += __shfl_down(n, o);
  if (lane == 0) normZ[row] = n * (-LOG2E / 16384.0f);  // pre-scaled
}

__device__ __forceinline__ int tri_start(int i) {
  return i * TILES - (i * (i - 1)) / 2;
}

__global__ __launch_bounds__(1024, 1) void mmd_mfma(
    const char* __restrict__ Zs, const float* __restrict__ normZ,
    double* __restrict__ sums) {
  // 2 bufs x (A 16 KB @ +0, B 16 KB @ +16384) = 64 KB (+pad).
  __shared__ alignas(16) char lds[2 * 32768 + 256];

  const int t = blockIdx.x;
  int I = (int)((129.0 - sqrt(129.0 * 129.0 - 8.0 * (double)t)) * 0.5);
  if (I > 63) I = 63;
  if (I < 0) I = 0;
  while (I < 63 && tri_start(I + 1) <= t) ++I;
  while (I > 0 && tri_start(I) > t) --I;
  const int J = I + (t - tri_start(I));

  const int tid = threadIdx.x;
  const int lane = tid & 63, wave = tid >> 6;      // 16 waves
  const int wr = wave >> 2, wc = wave & 3;         // 4x4 grid: 64x64/wave
  const int lr = lane & 15, quad = lane >> 4;      // MFMA lane decomposition

  // ---- staging geometry (contiguous 1-KB issues) ----
  // Wave w stages panel rows 16w..16w+15 for both A and B: source is
  // contiguous (Zs plane, pre-swizzled), dst = panel + w*1024 (linear).
  const char* srcA = Zs + (size_t)I * 16384 + wave * 1024 + (lane << 4);
  const char* srcB = Zs + (size_t)J * 16384 + wave * 1024 + (lane << 4);
  char* ldwA = lds + wave * 1024;                  // wave-uniform
  char* ldwB = lds + 16384 + wave * 1024;

#define STAGE(s, buf) do {                                               \
    gload_lds16(srcA + (size_t)(s) * PLANE, ldwA + (buf) * 32768);       \
    gload_lds16(srcB + (size_t)(s) * PLANE, ldwB + (buf) * 32768);       \
  } while (0)

  // ---- fragment read bases (r13-verified conflict-free swizzle) ----
  const int csw = (quad ^ ((lr >> 1) & 3)) << 4;
  const char* aRd = lds + (wr * 64 + lr) * 64 + csw;
  const char* bRd = lds + 16384 + (wc * 64 + lr) * 64 + csw;

  bf16x8 a[4], b[4];
  f32x4 acc[4][4] = {};

#define LOADFRAGS(buf) do {                                              \
    _Pragma("unroll")                                                    \
    for (int i = 0; i < 4; ++i)                                          \
      a[i] = *reinterpret_cast<const bf16x8*>(aRd + (buf) * 32768 + i * 1024); \
    _Pragma("unroll")                                                    \
    for (int j = 0; j < 4; ++j)                                          \
      b[j] = *reinterpret_cast<const bf16x8*>(bRd + (buf) * 32768 + j * 1024); \
  } while (0)

#define MFMAS() do {                                                     \
    _Pragma("unroll")                                                    \
    for (int i = 0; i < 4; ++i)                                          \
      _Pragma("unroll")                                                  \
      for (int j = 0; j < 4; ++j)                                        \
        acc[i][j] = __builtin_amdgcn_mfma_f32_16x16x32_bf16(             \
            a[i], b[j], acc[i][j], 0, 0, 0);                             \
  } while (0)

  // Prologue: 4 DMA issues in flight per wave (slices 0,1).
  STAGE(0, 0);
  STAGE(1, 1);

  // ---- slice 0 (buf0) ----
  asm volatile("s_waitcnt vmcnt(2)\n\ts_barrier" ::: "memory");
  LOADFRAGS(0);
  asm volatile("s_waitcnt lgkmcnt(0)\n\ts_barrier" ::: "memory");
  __builtin_amdgcn_sched_barrier(0);
  STAGE(2, 0);                       // safe: all waves done reading buf0
  __builtin_amdgcn_sched_barrier(0);
  MFMAS();

  // ---- slice 1 (buf1) ----
  asm volatile("s_waitcnt vmcnt(2)\n\ts_barrier" ::: "memory");
  LOADFRAGS(1);
  asm volatile("s_waitcnt lgkmcnt(0)\n\ts_barrier" ::: "memory");
  __builtin_amdgcn_sched_barrier(0);
  STAGE(3, 1);
  __builtin_amdgcn_sched_barrier(0);
  MFMAS();

  // ---- slice 2 (buf0, no restage) ----
  asm volatile("s_waitcnt vmcnt(2)\n\ts_barrier" ::: "memory");
  LOADFRAGS(0);
  asm volatile("s_waitcnt lgkmcnt(0)" ::: "memory");
  __builtin_amdgcn_sched_barrier(0);
  MFMAS();

  // ---- slice 3 (buf1, no restage) ----
  asm volatile("s_waitcnt vmcnt(0)\n\ts_barrier" ::: "memory");
  LOADFRAGS(1);
  asm volatile("s_waitcnt lgkmcnt(0)" ::: "memory");
  __builtin_amdgcn_sched_barrier(0);
  MFMAS();

#undef STAGE
#undef LOADFRAGS
#undef MFMAS

  // Norms (L2-hot, loaded after the MFMA pipeline).
  const float* nzA = normZ + I * 256 + wr * 64;
  const float* nzB = normZ + J * 256 + wc * 64;
  f32x4 ar[4];
  float cb[4];
#pragma unroll
  for (int i = 0; i < 4; ++i)
    ar[i] = *reinterpret_cast<const f32x4*>(nzA + i * 16 + quad * 4);
#pragma unroll
  for (int j = 0; j < 4; ++j) cb[j] = nzB[j * 16 + lr];

  // Epilogue (C/D: col=lane&15, row=quad*4+reg), packed fp32 pairs:
  // k = exp2(acc*S2 + ra + rb), ra/rb pre-scaled by -log2e/16384.
  const f32x2 s2v = {S2, S2};
  f32x2 part01 = {0.f, 0.f}, part23 = {0.f, 0.f};
#pragma unroll
  for (int i = 0; i < 4; ++i) {
    const f32x2 ar01 = {ar[i].x, ar[i].y};
    const f32x2 ar23 = {ar[i].z, ar[i].w};
#pragma unroll
    for (int j = 0; j < 4; ++j) {
      const f32x2 rb2 = {cb[j], cb[j]};
      const f32x2 base01 = ar01 + rb2;
      const f32x2 base23 = ar23 + rb2;
      const f32x2 acc01 = {acc[i][j][0], acc[i][j][1]};
      const f32x2 acc23 = {acc[i][j][2], acc[i][j][3]};
      const f32x2 arg01 = __builtin_elementwise_fma(acc01, s2v, base01);
      const f32x2 arg23 = __builtin_elementwise_fma(acc23, s2v, base23);
      part01 += (f32x2){EXP2F(arg01.x), EXP2F(arg01.y)};
      part23 += (f32x2){EXP2F(arg23.x), EXP2F(arg23.y)};
    }
  }
  const f32x2 ps = part01 + part23;
  double local = (double)(ps.x + ps.y);
  double w = ((I < 32) == (J < 32)) ? 1.0 : -1.0;  // X/Y boundary: tile 32
  if (I != J) w += w;
  local *= w;

#pragma unroll
  for (int o = 32; o > 0; o >>= 1) local += __shfl_down(local, o);
  if (lane == 0)
    atomicAdd(&sums[((t & 15) << 4) | wave], local);
}

__global__ void finish(const double* __restrict__ s, float* __restrict__ out) {
  double v = s[threadIdx.x] + s[threadIdx.x + 64] + s[threadIdx.x + 128] +
             s[threadIdx.x + 192];
#pragma unroll
  for (int o = 32; o > 0; o >>= 1) v += __shfl_down(v, o);
  if (threadIdx.x == 0)
    out[0] = (float)(v * (1.0 / ((double)NN * (double)NN)));
}

extern "C" void kernel_launch(void* const* d_in, const int* in_sizes, int n_in,
                              void* d_out, int out_size, void* d_ws, size_t ws_size,
                              hipStream_t stream) {
  const float* y_inputs = (const float*)d_in[0];  // "inputs"
  const float* x_true   = (const float*)d_in[1];  // "true_samples"
  float* out = (float*)d_out;

  char* ws = (char*)d_ws;
  double* sums = (double*)ws;                     // 256 fp64 partial slots
  float* normZ = (float*)(ws + WS_NORM);
  char* Zs = ws + WS_Z;

  prep<<<TZ / 4, 256, 0, stream>>>(x_true, y_inputs, Zs, normZ, sums);
  mmd_mfma<<<NBLOCKS, 1024, 0, stream>>>(Zs, normZ, sums);
  finish<<<1, 64, 0, stream>>>(sums, out);
}

// Round 6
// 108.404 us; speedup vs baseline: 1.0983x; 1.0983x over previous
//
#include <hip/hip_runtime.h>
#include <hip/hip_bf16.h>
#include <math.h>

// MMD (InfoVAE RBF kernel), N=8192, D=128, fp32 in, scalar fp32 out.
//
// Round 16 = r15 resubmitted verbatim (r15 bench died to container-infra
// failure before running; no kernel verdict). Audit found no HW-hang
// hazard: barriers block-uniform, vmcnt queue algebra closed-form sound,
// WAR overwrites all behind {lgkmcnt(0);barrier}, DMA in-bounds, LDS
// 50240 B x 3 blocks/CU fits.
//
// Round 15 design: persistent A-panel blocks; B-only sliced-dbuf staging.
//   r14 post-mortem: 4 structures all at 54-64us, no pipe saturated.
//   r14 halved DMA vs r10 yet was slower -> serialization exposure at
//   1 block/CU. Winning combo = fewer DMA bytes AT r10's occupancy.
//   Design: grid = 128 I-panels x 6 J-splits = 768 blocks, 3/CU
//   (LDS ~50 KB), 4 waves/block (r10 shape: 64x64/wave, acc[4][4]).
//   A panel (128 rows, all 4 K-planes, 32 KB) staged ONCE per block;
//   J-loop stages only B (K=32 slices, dbuf 2x8 KB) + 1 KB J-norms.
//   Total DMA 528 -> ~290 MB (~22 us/CU floor at ~21 B/cy).
//   Counted-vmcnt stream per wave per tile (queue oldest->newest):
//     entry [s0(2) s1(2)]  W0=vmcnt(2) -> issue s2(2)+norm(1)
//     [s1,s2,s2,nm]        W1=vmcnt(3) -> issue s3(2)
//     [s2,s2,nm,s3,s3]     W2=vmcnt(3) -> issue s0'(2)  (next tile)
//     [nm,s3,s3,s0',s0']   W3=vmcnt(2) (drains nm for epilogue) -> issue s1'(2)
//     epilogue (cb from LDS norms; no counted loads) -> entry state [s0',s1'].
//   Init drains vmcnt(0) once (queue<=steady => all waits remain safe).
//   Last tile stages a clamped (redundant) next-J - keeps stream uniform.
//   Epilogue ar (I-norms) hoisted pre-loop; cb (J-norms) via DMA->LDS,
//   so no compiler global loads interleave the counted waits.
//   All fragment addressing / swizzle / MFMA chain / epilogue math are
//   bit-identical to r14 (passed 5.96e-8): plane layout pre-swizzles
//   chunk c^((row>>1)&3) at prep store; read csw=(quad^((lr>>1)&3))<<4
//   (measured 0 conflicts). Per-element K-chain: 4x 16x16x32 ascending.
//   fp64 per-wave accumulation across tiles (reorder only, ~1e-16).

#define NN 8192
#define DD 128
#define TZ 16384
#define SPLIT 6
#define NBLK (128 * SPLIT)                 // 768

typedef __attribute__((ext_vector_type(8))) short bf16x8;
typedef __attribute__((ext_vector_type(4))) float f32x4;
typedef __attribute__((ext_vector_type(2))) float f32x2;

#if __has_builtin(__builtin_amdgcn_exp2f)
#define EXP2F __builtin_amdgcn_exp2f
#else
#define EXP2F exp2f
#endif

constexpr float LOG2E = 0x1.715476p+0f;
constexpr float S2 = LOG2E / 8192.0f;              // 2*log2e/16384

constexpr size_t PLANE = 1048576;                  // 16384 rows x 64 B

// lds offsets: A planes 0..32767 (4 x 8 KB); B bufs 32768 + buf*8192;
// J-norms 49152..50175; reduction scratch 50176.
#define LDS_B 32768
#define LDS_NORM 49152
#define LDS_RED 50176

// ---- ws layout ----
constexpr size_t WS_NORM = 2048;                   // sums: 256 fp64 slots
constexpr size_t WS_Z    = WS_NORM + (size_t)TZ * sizeof(float);

__device__ __forceinline__ void gload_lds16(const void* g, void* l) {
  __builtin_amdgcn_global_load_lds(
      (const __attribute__((address_space(1))) void*)g,
      (__attribute__((address_space(3))) void*)l, 16, 0, 0);
}

__global__ __launch_bounds__(256) void prep(
    const float* __restrict__ X, const float* __restrict__ Y,
    char* __restrict__ Zs, float* __restrict__ normZ,
    double* __restrict__ sums) {
  if (blockIdx.x == 0) sums[threadIdx.x] = 0.0;    // 256 slots

  const int row = blockIdx.x * 4 + (threadIdx.x >> 6);
  const int lane = threadIdx.x & 63;
  const float* __restrict__ src =
      (row < NN) ? (X + (size_t)row * DD) : (Y + (size_t)(row - NN) * DD);
  const float2 v = *reinterpret_cast<const float2*>(src + 2 * lane);

  float n = v.x * v.x + v.y * v.y;

  // K-slice plane store, chunk pre-swizzled (r14-verified).
  const int ks = lane >> 4;
  const int quadc = (lane >> 2) & 3;
  const int inner = (lane & 3) * 4;
  char* dst = Zs + (size_t)ks * PLANE + (size_t)row * 64 +
              ((quadc ^ ((row >> 1) & 3)) << 4) + inner;
  *reinterpret_cast<__hip_bfloat162*>(dst) =
      __hip_bfloat162{__float2bfloat16(v.x), __float2bfloat16(v.y)};

#pragma unroll
  for (int o = 32; o > 0; o >>= 1) n += __shfl_down(n, o);
  if (lane == 0) normZ[row] = n * (-LOG2E / 16384.0f);  // pre-scaled
}

__global__ __launch_bounds__(256, 3) void mmd_mfma(
    const char* __restrict__ Zs, const float* __restrict__ normZ,
    double* __restrict__ sums) {
  __shared__ alignas(16) char lds[50176 + 64];

  const int bid = blockIdx.x;
  const int I = bid / SPLIT, s6 = bid % SPLIT;
  const int rem = 127 - I - s6;
  if (rem < 0) return;                             // empty block (uniform)
  const int nIter = rem / SPLIT + 1;

  const int tid = threadIdx.x;
  const int lane = tid & 63, wave = tid >> 6;      // 4 waves
  const int wr = wave >> 1, wc = wave & 1;         // 2x2 grid: 64x64/wave
  const int lr = lane & 15, quad = lane >> 4;

  // ---- hoisted I-side norms (drained by the init vmcnt(0)) ----
  const float* nzA = normZ + I * 128 + wr * 64;
  f32x4 ar[4];
#pragma unroll
  for (int i = 0; i < 4; ++i)
    ar[i] = *reinterpret_cast<const f32x4*>(nzA + i * 16 + quad * 4);

  // ---- stage A panel: 4 planes x 8 KB, 2 issues/wave/plane ----
  const char* srcA0 = Zs + (size_t)(I * 128 + wave * 32) * 64 + lane * 16;
  char* ldwA = lds + wave * 2048;
#pragma unroll
  for (int ks = 0; ks < 4; ++ks) {
    gload_lds16(srcA0 + (size_t)ks * PLANE,        ldwA + ks * 8192);
    gload_lds16(srcA0 + (size_t)ks * PLANE + 1024, ldwA + ks * 8192 + 1024);
  }

  int J = I + s6;
  const char* srcB = Zs + (size_t)(J * 128 + wave * 32) * 64 + lane * 16;
  const char* normB = (const char*)normZ + (size_t)J * 512 + lane * 16;

#define STAGE_B(base, s, buf) do {                                          \
    gload_lds16((base) + (size_t)(s) * PLANE,                               \
                lds + LDS_B + (buf) * 8192 + wave * 2048);                  \
    gload_lds16((base) + (size_t)(s) * PLANE + 1024,                        \
                lds + LDS_B + (buf) * 8192 + wave * 2048 + 1024);           \
  } while (0)

  // Prologue B slices 0,1; then one-time full drain (queue<=steady-state
  // afterwards, so all counted waits below remain safe).
  STAGE_B(srcB, 0, 0);
  STAGE_B(srcB, 1, 1);
  asm volatile("s_waitcnt vmcnt(0)\n\ts_barrier" ::: "memory");

  // ---- fragment read bases (r13/r14-verified conflict-free swizzle) ----
  const int csw = (quad ^ ((lr >> 1) & 3)) << 4;
  const char* aRd = lds + (wr * 64 + lr) * 64 + csw;
  const char* bRd = lds + LDS_B + (wc * 64 + lr) * 64 + csw;

  bf16x8 a[4], b[4];

#define LOADFRAGS(ks, buf) do {                                             \
    _Pragma("unroll")                                                       \
    for (int i = 0; i < 4; ++i)                                             \
      a[i] = *reinterpret_cast<const bf16x8*>(aRd + (ks) * 8192 + i * 1024);\
    _Pragma("unroll")                                                       \
    for (int j = 0; j < 4; ++j)                                             \
      b[j] = *reinterpret_cast<const bf16x8*>(bRd + (buf) * 8192 + j * 1024);\
  } while (0)

#define MFMAS() do {                                                        \
    __builtin_amdgcn_s_setprio(1);                                          \
    _Pragma("unroll")                                                       \
    for (int i = 0; i < 4; ++i)                                             \
      _Pragma("unroll")                                                     \
      for (int j = 0; j < 4; ++j)                                           \
        acc[i][j] = __builtin_amdgcn_mfma_f32_16x16x32_bf16(                \
            a[i], b[j], acc[i][j], 0, 0, 0);                                \
    __builtin_amdgcn_s_setprio(0);                                          \
  } while (0)

  const f32x2 s2v = {S2, S2};
  double blockAcc = 0.0;

  for (int it = 0; it < nIter; ++it) {
    // Last tile stages a clamped (redundant) next-J: uniform vmcnt stream.
    const char* srcBn = (it + 1 < nIter) ? srcB + SPLIT * 8192 : srcB;
    f32x4 acc[4][4] = {};

    // ---- slice 0 (A plane 0, B buf0) ----
    asm volatile("s_waitcnt vmcnt(2)\n\ts_barrier" ::: "memory");
    LOADFRAGS(0, 0);
    asm volatile("s_waitcnt lgkmcnt(0)\n\ts_barrier" ::: "memory");
    __builtin_amdgcn_sched_barrier(0);
    STAGE_B(srcB, 2, 0);
    gload_lds16(normB, lds + LDS_NORM);            // J-norms (1 KB, dup x4)
    __builtin_amdgcn_sched_barrier(0);
    MFMAS();

    // ---- slice 1 (plane 1, buf1) ----
    asm volatile("s_waitcnt vmcnt(3)\n\ts_barrier" ::: "memory");
    LOADFRAGS(1, 1);
    asm volatile("s_waitcnt lgkmcnt(0)\n\ts_barrier" ::: "memory");
    __builtin_amdgcn_sched_barrier(0);
    STAGE_B(srcB, 3, 1);
    __builtin_amdgcn_sched_barrier(0);
    MFMAS();

    // ---- slice 2 (plane 2, buf0) ----
    asm volatile("s_waitcnt vmcnt(3)\n\ts_barrier" ::: "memory");
    LOADFRAGS(2, 0);
    asm volatile("s_waitcnt lgkmcnt(0)\n\ts_barrier" ::: "memory");
    __builtin_amdgcn_sched_barrier(0);
    STAGE_B(srcBn, 0, 0);                          // next tile s0
    __builtin_amdgcn_sched_barrier(0);
    MFMAS();

    // ---- slice 3 (plane 3, buf1) ----  (vmcnt(2) also drains norms)
    asm volatile("s_waitcnt vmcnt(2)\n\ts_barrier" ::: "memory");
    LOADFRAGS(3, 1);
    asm volatile("s_waitcnt lgkmcnt(0)\n\ts_barrier" ::: "memory");
    __builtin_amdgcn_sched_barrier(0);
    STAGE_B(srcBn, 1, 1);                          // next tile s1
    __builtin_amdgcn_sched_barrier(0);
    MFMAS();

    // ---- epilogue: cb from LDS norms; no counted loads ----
    float cb[4];
#pragma unroll
    for (int j = 0; j < 4; ++j)
      cb[j] = *reinterpret_cast<const float*>(
          lds + LDS_NORM + (wc * 64 + j * 16 + lr) * 4);

    f32x2 part01 = {0.f, 0.f}, part23 = {0.f, 0.f};
#pragma unroll
    for (int i = 0; i < 4; ++i) {
      const f32x2 ar01 = {ar[i].x, ar[i].y};
      const f32x2 ar23 = {ar[i].z, ar[i].w};
#pragma unroll
      for (int j = 0; j < 4; ++j) {
        const f32x2 rb2 = {cb[j], cb[j]};
        const f32x2 base01 = ar01 + rb2;
        const f32x2 base23 = ar23 + rb2;
        const f32x2 acc01 = {acc[i][j][0], acc[i][j][1]};
        const f32x2 acc23 = {acc[i][j][2], acc[i][j][3]};
        const f32x2 arg01 = __builtin_elementwise_fma(acc01, s2v, base01);
        const f32x2 arg23 = __builtin_elementwise_fma(acc23, s2v, base23);
        part01 += (f32x2){EXP2F(arg01.x), EXP2F(arg01.y)};
        part23 += (f32x2){EXP2F(arg23.x), EXP2F(arg23.y)};
      }
    }
    const f32x2 ps = part01 + part23;
    double w = ((I < 64) == (J < 64)) ? 1.0 : -1.0;  // X/Y boundary: tile 64
    if (I != J) w += w;
    blockAcc += (double)(ps.x + ps.y) * w;

    J += SPLIT;
    srcB += SPLIT * 8192;
    normB += SPLIT * 512;
  }

#undef STAGE_B
#undef LOADFRAGS
#undef MFMAS

  // Drain the clamped trailing stages, then reduce.
  asm volatile("s_waitcnt vmcnt(0)" ::: "memory");
#pragma unroll
  for (int o = 32; o > 0; o >>= 1) blockAcc += __shfl_down(blockAcc, o);
  double* red = reinterpret_cast<double*>(lds + LDS_RED);
  if (lane == 0) red[wave] = blockAcc;
  __syncthreads();
  if (tid == 0)
    atomicAdd(&sums[bid & 255], red[0] + red[1] + red[2] + red[3]);
}

__global__ void finish(const double* __restrict__ s, float* __restrict__ out) {
  double v = s[threadIdx.x] + s[threadIdx.x + 64] + s[threadIdx.x + 128] +
             s[threadIdx.x + 192];
#pragma unroll
  for (int o = 32; o > 0; o >>= 1) v += __shfl_down(v, o);
  if (threadIdx.x == 0)
    out[0] = (float)(v * (1.0 / ((double)NN * (double)NN)));
}

extern "C" void kernel_launch(void* const* d_in, const int* in_sizes, int n_in,
                              void* d_out, int out_size, void* d_ws, size_t ws_size,
                              hipStream_t stream) {
  const float* y_inputs = (const float*)d_in[0];  // "inputs"
  const float* x_true   = (const float*)d_in[1];  // "true_samples"
  float* out = (float*)d_out;

  char* ws = (char*)d_ws;
  double* sums = (double*)ws;                     // 256 fp64 partial slots
  float* normZ = (float*)(ws + WS_NORM);
  char* Zs = ws + WS_Z;

  prep<<<TZ / 4, 256, 0, stream>>>(x_true, y_inputs, Zs, normZ, sums);
  mmd_mfma<<<NBLK, 256, 0, stream>>>(Zs, normZ, sums);
  finish<<<1, 64, 0, stream>>>(sums, out);
}

// Round 7
// 102.047 us; speedup vs baseline: 1.1667x; 1.0623x over previous
//
#include <hip/hip_runtime.h>
#include <hip/hip_bf16.h>
#include <math.h>

// MMD (InfoVAE RBF kernel), N=8192, D=128, fp32 in, scalar fp32 out.
//
// Round 17: triangle-PAIRED load balancing of the r15/r16 pipeline.
//   r16 post-mortem: 50.7us, MfmaUtil 26%, Occupancy 20.8%. Grid=768 =
//   exactly 3 blocks/CU -> ALL blocks co-resident, zero rebalancing; r15
//   strips are 1..22 tiles -> runtime == max block (22 tiles ~= 50.7us),
//   average block only 10.75 tiles (~25us). Scheduling, not pipeline.
//   Fix: pair strip p with strip 127-p: (128-p) + (p+1) = 129 tiles per
//   pair, constant. Grid = 64 pairs x 12 splits = 768 blocks (3/CU, all
//   resident); block (p,s) takes virtual tiles v = s+12k of the pair's
//   129-list -> 10 or 11 tiles/block (was 5..22). Two segments per block
//   (one per strip), each = the r15-verified pipeline verbatim:
//   A-panel (32 KB, 4 planes) staged once per segment; B K=32-sliced
//   dbuf 2x8 KB + 1 KB J-norms via DMA; counted-vmcnt stream per tile
//   (entry [s0,s1] -> W2/W3/W3/W2 -> exit [s0',s1']); segment entry with
//   empty queue makes counted waits trivially safe; segment-end
//   {vmcnt(0);barrier} protects A/B/norm LDS overwrites (all LDS-read
//   consumers precede the barrier in program order).
//   Swizzle / fragment addressing / MFMA K-chain / epilogue math are
//   bit-identical to r16 (passed 5.96e-8): plane layout pre-swizzles
//   chunk c^((row>>1)&3) at prep store; read csw=(quad^((lr>>1)&3))<<4
//   (measured 0 conflicts). Only fp64 summation order changes (~1e-16).

#define NN 8192
#define DD 128
#define TZ 16384
#define SPLIT 12
#define NBLK (64 * SPLIT)                  // 768

typedef __attribute__((ext_vector_type(8))) short bf16x8;
typedef __attribute__((ext_vector_type(4))) float f32x4;
typedef __attribute__((ext_vector_type(2))) float f32x2;

#if __has_builtin(__builtin_amdgcn_exp2f)
#define EXP2F __builtin_amdgcn_exp2f
#else
#define EXP2F exp2f
#endif

constexpr float LOG2E = 0x1.715476p+0f;
constexpr float S2 = LOG2E / 8192.0f;              // 2*log2e/16384

constexpr size_t PLANE = 1048576;                  // 16384 rows x 64 B

// lds offsets: A planes 0..32767 (4 x 8 KB); B bufs 32768 + buf*8192;
// J-norms 49152..50175; reduction scratch 50176.
#define LDS_B 32768
#define LDS_NORM 49152
#define LDS_RED 50176

// ---- ws layout ----
constexpr size_t WS_NORM = 2048;                   // sums: 256 fp64 slots
constexpr size_t WS_Z    = WS_NORM + (size_t)TZ * sizeof(float);

__device__ __forceinline__ void gload_lds16(const void* g, void* l) {
  __builtin_amdgcn_global_load_lds(
      (const __attribute__((address_space(1))) void*)g,
      (__attribute__((address_space(3))) void*)l, 16, 0, 0);
}

__global__ __launch_bounds__(256) void prep(
    const float* __restrict__ X, const float* __restrict__ Y,
    char* __restrict__ Zs, float* __restrict__ normZ,
    double* __restrict__ sums) {
  if (blockIdx.x == 0) sums[threadIdx.x] = 0.0;    // 256 slots

  const int row = blockIdx.x * 4 + (threadIdx.x >> 6);
  const int lane = threadIdx.x & 63;
  const float* __restrict__ src =
      (row < NN) ? (X + (size_t)row * DD) : (Y + (size_t)(row - NN) * DD);
  const float2 v = *reinterpret_cast<const float2*>(src + 2 * lane);

  float n = v.x * v.x + v.y * v.y;

  // K-slice plane store, chunk pre-swizzled (r14-verified).
  const int ks = lane >> 4;
  const int quadc = (lane >> 2) & 3;
  const int inner = (lane & 3) * 4;
  char* dst = Zs + (size_t)ks * PLANE + (size_t)row * 64 +
              ((quadc ^ ((row >> 1) & 3)) << 4) + inner;
  *reinterpret_cast<__hip_bfloat162*>(dst) =
      __hip_bfloat162{__float2bfloat16(v.x), __float2bfloat16(v.y)};

#pragma unroll
  for (int o = 32; o > 0; o >>= 1) n += __shfl_down(n, o);
  if (lane == 0) normZ[row] = n * (-LOG2E / 16384.0f);  // pre-scaled
}

__global__ __launch_bounds__(256, 3) void mmd_mfma(
    const char* __restrict__ Zs, const float* __restrict__ normZ,
    double* __restrict__ sums) {
  __shared__ alignas(16) char lds[50176 + 64];

  const int bid = blockIdx.x;
  const int p = bid / SPLIT, s = bid % SPLIT;
  const int q = 127 - p;
  // Segment 0: strip I=p, virtual v = s+12k, v <= 127-p (n1 >= 5 always).
  const int n1 = (127 - p - s) / 12 + 1;
  // Segment 1: strip I=q, u = v-(128-p) for the first v >= 128-p.
  const int u0 = s + 12 * n1 - (128 - p);            // >= 0 by construction
  const int n2 = (u0 <= p) ? (p - u0) / 12 + 1 : 0;

  const int segI[2]  = {p, q};
  const int segJ0[2] = {p + s, q + u0};
  const int segN[2]  = {n1, n2};

  const int tid = threadIdx.x;
  const int lane = tid & 63, wave = tid >> 6;      // 4 waves
  const int wr = wave >> 1, wc = wave & 1;         // 2x2 grid: 64x64/wave
  const int lr = lane & 15, quad = lane >> 4;

  char* ldwA = lds + wave * 2048;

  // ---- fragment read bases (r13/r14-verified conflict-free swizzle) ----
  const int csw = (quad ^ ((lr >> 1) & 3)) << 4;
  const char* aRd = lds + (wr * 64 + lr) * 64 + csw;
  const char* bRd = lds + LDS_B + (wc * 64 + lr) * 64 + csw;

  bf16x8 a[4], b[4];
  f32x4 ar[4];

#define STAGE_B(base, sl, buf) do {                                         \
    gload_lds16((base) + (size_t)(sl) * PLANE,                              \
                lds + LDS_B + (buf) * 8192 + wave * 2048);                  \
    gload_lds16((base) + (size_t)(sl) * PLANE + 1024,                       \
                lds + LDS_B + (buf) * 8192 + wave * 2048 + 1024);           \
  } while (0)

#define LOADFRAGS(ks, buf) do {                                             \
    _Pragma("unroll")                                                       \
    for (int i = 0; i < 4; ++i)                                             \
      a[i] = *reinterpret_cast<const bf16x8*>(aRd + (ks) * 8192 + i * 1024);\
    _Pragma("unroll")                                                       \
    for (int j = 0; j < 4; ++j)                                             \
      b[j] = *reinterpret_cast<const bf16x8*>(bRd + (buf) * 8192 + j * 1024);\
  } while (0)

#define MFMAS() do {                                                        \
    __builtin_amdgcn_s_setprio(1);                                          \
    _Pragma("unroll")                                                       \
    for (int i = 0; i < 4; ++i)                                             \
      _Pragma("unroll")                                                     \
      for (int j = 0; j < 4; ++j)                                           \
        acc[i][j] = __builtin_amdgcn_mfma_f32_16x16x32_bf16(                \
            a[i], b[j], acc[i][j], 0, 0, 0);                                \
    __builtin_amdgcn_s_setprio(0);                                          \
  } while (0)

  const f32x2 s2v = {S2, S2};
  double blockAcc = 0.0;

  for (int seg = 0; seg < 2; ++seg) {
    const int I = segI[seg];
    const int nIter = segN[seg];
    if (nIter == 0) continue;                      // block-uniform
    int J = segJ0[seg];

    // ---- hoisted I-side norms (drained before use by consumer waits) ----
    const float* nzA = normZ + I * 128 + wr * 64;
#pragma unroll
    for (int i = 0; i < 4; ++i)
      ar[i] = *reinterpret_cast<const f32x4*>(nzA + i * 16 + quad * 4);

    // ---- stage A panel: 4 planes x 8 KB, 2 issues/wave/plane ----
    // (A-region overwrite protected by previous segment-end barrier.)
    const char* srcA0 = Zs + (size_t)(I * 128 + wave * 32) * 64 + lane * 16;
#pragma unroll
    for (int ks = 0; ks < 4; ++ks) {
      gload_lds16(srcA0 + (size_t)ks * PLANE,        ldwA + ks * 8192);
      gload_lds16(srcA0 + (size_t)ks * PLANE + 1024, ldwA + ks * 8192 + 1024);
    }

    const char* srcB = Zs + (size_t)(J * 128 + wave * 32) * 64 + lane * 16;
    const char* normB = (const char*)normZ + (size_t)J * 512 + lane * 16;

    // Prologue B slices 0,1; one-time full drain -> counted waits below
    // enter with an empty queue (trivially safe) and establish steady state.
    STAGE_B(srcB, 0, 0);
    STAGE_B(srcB, 1, 1);
    asm volatile("s_waitcnt vmcnt(0)\n\ts_barrier" ::: "memory");

    for (int it = 0; it < nIter; ++it) {
      // Last tile stages a clamped (redundant) next-J: uniform vmcnt stream.
      const char* srcBn = (it + 1 < nIter) ? srcB + SPLIT * 8192 : srcB;
      f32x4 acc[4][4] = {};

      // ---- slice 0 (A plane 0, B buf0) ----
      asm volatile("s_waitcnt vmcnt(2)\n\ts_barrier" ::: "memory");
      LOADFRAGS(0, 0);
      asm volatile("s_waitcnt lgkmcnt(0)\n\ts_barrier" ::: "memory");
      __builtin_amdgcn_sched_barrier(0);
      STAGE_B(srcB, 2, 0);
      gload_lds16(normB, lds + LDS_NORM);          // J-norms (1 KB, dup x4)
      __builtin_amdgcn_sched_barrier(0);
      MFMAS();

      // ---- slice 1 (plane 1, buf1) ----
      asm volatile("s_waitcnt vmcnt(3)\n\ts_barrier" ::: "memory");
      LOADFRAGS(1, 1);
      asm volatile("s_waitcnt lgkmcnt(0)\n\ts_barrier" ::: "memory");
      __builtin_amdgcn_sched_barrier(0);
      STAGE_B(srcB, 3, 1);
      __builtin_amdgcn_sched_barrier(0);
      MFMAS();

      // ---- slice 2 (plane 2, buf0) ----
      asm volatile("s_waitcnt vmcnt(3)\n\ts_barrier" ::: "memory");
      LOADFRAGS(2, 0);
      asm volatile("s_waitcnt lgkmcnt(0)\n\ts_barrier" ::: "memory");
      __builtin_amdgcn_sched_barrier(0);
      STAGE_B(srcBn, 0, 0);                        // next tile s0
      __builtin_amdgcn_sched_barrier(0);
      MFMAS();

      // ---- slice 3 (plane 3, buf1) ----  (vmcnt(2) also drains norms)
      asm volatile("s_waitcnt vmcnt(2)\n\ts_barrier" ::: "memory");
      LOADFRAGS(3, 1);
      asm volatile("s_waitcnt lgkmcnt(0)\n\ts_barrier" ::: "memory");
      __builtin_amdgcn_sched_barrier(0);
      STAGE_B(srcBn, 1, 1);                        // next tile s1
      __builtin_amdgcn_sched_barrier(0);
      MFMAS();

      // ---- epilogue: cb from LDS norms; no counted loads ----
      float cb[4];
#pragma unroll
      for (int j = 0; j < 4; ++j)
        cb[j] = *reinterpret_cast<const float*>(
            lds + LDS_NORM + (wc * 64 + j * 16 + lr) * 4);

      f32x2 part01 = {0.f, 0.f}, part23 = {0.f, 0.f};
#pragma unroll
      for (int i = 0; i < 4; ++i) {
        const f32x2 ar01 = {ar[i].x, ar[i].y};
        const f32x2 ar23 = {ar[i].z, ar[i].w};
#pragma unroll
        for (int j = 0; j < 4; ++j) {
          const f32x2 rb2 = {cb[j], cb[j]};
          const f32x2 base01 = ar01 + rb2;
          const f32x2 base23 = ar23 + rb2;
          const f32x2 acc01 = {acc[i][j][0], acc[i][j][1]};
          const f32x2 acc23 = {acc[i][j][2], acc[i][j][3]};
          const f32x2 arg01 = __builtin_elementwise_fma(acc01, s2v, base01);
          const f32x2 arg23 = __builtin_elementwise_fma(acc23, s2v, base23);
          part01 += (f32x2){EXP2F(arg01.x), EXP2F(arg01.y)};
          part23 += (f32x2){EXP2F(arg23.x), EXP2F(arg23.y)};
        }
      }
      const f32x2 ps = part01 + part23;
      double w = ((I < 64) == (J < 64)) ? 1.0 : -1.0;  // X/Y boundary: 64
      if (I != J) w += w;
      blockAcc += (double)(ps.x + ps.y) * w;

      J += SPLIT;
      srcB += SPLIT * 8192;
      normB += SPLIT * 512;
    }

    // Segment-end: drain clamped trailing stages; barrier so the next
    // segment's A/B/norm staging cannot overwrite LDS still being read.
    asm volatile("s_waitcnt vmcnt(0)\n\ts_barrier" ::: "memory");
  }

#undef STAGE_B
#undef LOADFRAGS
#undef MFMAS

#pragma unroll
  for (int o = 32; o > 0; o >>= 1) blockAcc += __shfl_down(blockAcc, o);
  double* red = reinterpret_cast<double*>(lds + LDS_RED);
  if (lane == 0) red[wave] = blockAcc;
  __syncthreads();
  if (tid == 0)
    atomicAdd(&sums[bid & 255], red[0] + red[1] + red[2] + red[3]);
}

__global__ void finish(const double* __restrict__ s, float* __restrict__ out) {
  double v = s[threadIdx.x] + s[threadIdx.x + 64] + s[threadIdx.x + 128] +
             s[threadIdx.x + 192];
#pragma unroll
  for (int o = 32; o > 0; o >>= 1) v += __shfl_down(v, o);
  if (threadIdx.x == 0)
    out[0] = (float)(v * (1.0 / ((double)NN * (double)NN)));
}

extern "C" void kernel_launch(void* const* d_in, const int* in_sizes, int n_in,
                              void* d_out, int out_size, void* d_ws, size_t ws_size,
                              hipStream_t stream) {
  const float* y_inputs = (const float*)d_in[0];  // "inputs"
  const float* x_true   = (const float*)d_in[1];  // "true_samples"
  float* out = (float*)d_out;

  char* ws = (char*)d_ws;
  double* sums = (double*)ws;                     // 256 fp64 partial slots
  float* normZ = (float*)(ws + WS_NORM);
  char* Zs = ws + WS_Z;

  prep<<<TZ / 4, 256, 0, stream>>>(x_true, y_inputs, Zs, normZ, sums);
  mmd_mfma<<<NBLK, 256, 0, stream>>>(Zs, normZ, sums);
  finish<<<1, 64, 0, stream>>>(sums, out);
}